// Round 5
// baseline (912.947 us; speedup 1.0000x reference)
//
#include <hip/hip_runtime.h>
#include <math.h>

// B=32, R=16384, C=16, IC=16, OC=16, 3 routing iterations.
// x: (B,C,IC) fp32 [8192]; W: (R,C,OC,IC) fp32 [67108864 = 256 MB]; out: (B,C,OC) fp32.
//
// Algebra: b after iter2 = <u,v1>, after iter3 = <u,v1+v2>, so no logit array is
// needed -- both routing passes are the same kernel with a different v vector.
//
// History: R1/R4 (8 waves, 4 b/wave) = 221/170 us/pass: live set ~163 regs vs 128
// arch-VGPRs -> compiler shuttles overflow through AGPRs (VALU inflation) and only
// 2 waves/SIMD (128 KB LDS, 1 block/CU) -> 54% lgkmcnt-stall. R2/R3 restructures
// spilled to scratch (0.7-3.9 GB). This round: 16 waves x 2 b/wave, live ~95 regs
// -> genuinely fits 128 VGPR at 4 waves/SIMD; same dbuf/XOR-LDS/unroll structure.

#define RT 16384

// dot of 4 float4 (VGPR) against 16 scalars (SGPR) -- v_fmac v,s,v is legal.
#define DOT16S(w0,w1,w2,w3,xs) \
  (w0.x*xs[0] + w0.y*xs[1] + w0.z*xs[2] + w0.w*xs[3] + \
   w1.x*xs[4] + w1.y*xs[5] + w1.z*xs[6] + w1.w*xs[7] + \
   w2.x*xs[8] + w2.y*xs[9] + w2.z*xs[10] + w2.w*xs[11] + \
   w3.x*xs[12] + w3.y*xs[13] + w3.z*xs[14] + w3.w*xs[15])

// async global->LDS, 16 B per lane. LDS dest = wave-uniform base + lane*16.
__device__ __forceinline__ void gload_lds16(const void* g, void* l) {
  __builtin_amdgcn_global_load_lds(
      (const __attribute__((address_space(1))) unsigned int*)g,
      (__attribute__((address_space(3))) unsigned int*)l, 16, 0, 0);
}

__device__ __forceinline__ float rfl(float v) {
  return __uint_as_float(__builtin_amdgcn_readfirstlane(__float_as_uint(v)));
}

// ---------------------------------------------------------------------------
// K1: partial W-sums, NO atomics. part[p][cls4] (float4), p = r-part [0,256),
// each part covers 64 consecutive r. Fully coalesced.
// ---------------------------------------------------------------------------
__global__ __launch_bounds__(256) void k_wsum(const float4* __restrict__ W4,
                                              float4* __restrict__ part) {
    int g = blockIdx.x & 3;                        // cls4 group [0,4)
    int p = blockIdx.x >> 2;                       // r-part    [0,256)
    int cls4 = g * 256 + threadIdx.x;              // [0,1024)
    const float4* base = W4 + (size_t)p * 64 * 1024 + cls4;
    float4 acc = {0.f, 0.f, 0.f, 0.f};
    #pragma unroll 8
    for (int rr = 0; rr < 64; ++rr) {
        float4 w = base[(size_t)rr * 1024];
        acc.x += w.x; acc.y += w.y; acc.z += w.z; acc.w += w.w;
    }
    part[p * 1024 + cls4] = acc;
}

// ---------------------------------------------------------------------------
// k_wred_v1: fused partial-reduction + v1.  Grid = 16 blocks (one per c).
// ---------------------------------------------------------------------------
__global__ __launch_bounds__(256) void k_wred_v1(const float* __restrict__ part,
                                                 const float* __restrict__ x,
                                                 float* __restrict__ v1) {
    __shared__ float ws[256];
    int c = blockIdx.x, t = threadIdx.x;
    float acc = 0.f;
    #pragma unroll 8
    for (int p = 0; p < 256; ++p) acc += part[p * 4096 + c * 256 + t];
    ws[t] = acc;
    __syncthreads();
    int o = t & 15;
    #pragma unroll
    for (int bb = 0; bb < 2; ++bb) {
        int b = (t >> 4) + bb * 16;
        const float* xb = x + (b * 16 + c) * 16;
        float s = 0.f;
        #pragma unroll
        for (int i = 0; i < 16; ++i) s += ws[o * 16 + i] * xb[i];
        s *= (1.0f / 16384.0f);
        float ns = s * s;
        #pragma unroll
        for (int d = 1; d < 16; d <<= 1) ns += __shfl_xor(ns, d);
        v1[b * 256 + c * 16 + o] = s * (sqrtf(ns) / (1.0f + ns));
    }
}

// k_vsum: v2 = squash(E/Z); vsum = v1 + v2
__global__ __launch_bounds__(256) void k_vsum(const float* __restrict__ E,
                                              const float* __restrict__ Z,
                                              const float* __restrict__ v1,
                                              float* __restrict__ vsum) {
    int t = blockIdx.x * 256 + threadIdx.x;
    float s = E[t] / Z[t >> 4];
    float ns = s * s;
    #pragma unroll
    for (int d = 1; d < 16; d <<= 1) ns += __shfl_xor(ns, d);
    vsum[t] = v1[t] + s * (sqrtf(ns) / (1.0f + ns));
}

// k_vout: final v = squash(E/Z) -> out
__global__ __launch_bounds__(256) void k_vout(const float* __restrict__ E,
                                              const float* __restrict__ Z,
                                              float* __restrict__ dst) {
    int t = blockIdx.x * 256 + threadIdx.x;
    float s = E[t] / Z[t >> 4];
    float ns = s * s;
    #pragma unroll
    for (int d = 1; d < 16; d <<= 1) ns += __shfl_xor(ns, d);
    dst[t] = s * (sqrtf(ns) / (1.0f + ns));
}

// ---------------------------------------------------------------------------
// k_route: one routing pass.
//   u[o] = sum_i W[r,c,o,i]*x[b,c,i];  e = exp(<u,v>);  E += e*u;  Z += e.
// Block 1024 = 16 waves; wave wv owns b in {2wv, 2wv+1}; lane = r within the
// 64-row chunk; 4 chunks, 128 KB LDS double buffer, prefetch-then-compute.
// LDS float4-XOR swizzle: slot rl*64+l holds row rl's float4 (l^rl); within
// every 8-lane group the bank-quads are distinct -> b128 reads at the floor.
// x AND v in SGPRs (wave-uniform, readfirstlane): live VGPRs ~95 -> fits the
// 128-VGPR budget of __launch_bounds__(1024,4) (4 waves/SIMD) with no AGPR
// shuttling (R4's hidden VALU tax) and no scratch (R2/R3's failure).
// REV: pass 2 walks r backwards (k_wsum ends at high r; L3 ~ |W|).
// ---------------------------------------------------------------------------
template <int REV>
__global__ __launch_bounds__(1024, 4)
void k_route(const float* __restrict__ W,
             const float* __restrict__ x,
             const float* __restrict__ v,
             float* __restrict__ E,
             float* __restrict__ Z) {
    __shared__ float4 Wl[2][64 * 64];              // 128 KB double buffer
    const int c = blockIdx.y;
    const int bx = REV ? (63 - (int)blockIdx.x) : (int)blockIdx.x;
    const int r0 = bx * 256;
    const int tid = threadIdx.x;
    const int wv = __builtin_amdgcn_readfirstlane(tid >> 6);   // [0,16)
    const int lane = tid & 63;

    const float4* W4c = (const float4*)W + c * 64; // + r*1024 + j

    // x and v rows for this wave's 2 b's -> SGPRs (wave-uniform)
    float xs[2][16];
    float vs[2][16];
    #pragma unroll
    for (int bl = 0; bl < 2; ++bl) {
        const float* xb = x + ((wv * 2 + bl) * 16 + c) * 16;
        const float* vb = v + ((wv * 2 + bl) * 16 + c) * 16;
        #pragma unroll
        for (int i = 0; i < 16; ++i) {
            xs[bl][i] = rfl(xb[i]);
            vs[bl][i] = rfl(vb[i]);
        }
    }

    float accE[2][16];
    float accZ[2] = {0.f, 0.f};
    #pragma unroll
    for (int bl = 0; bl < 2; ++bl)
        #pragma unroll
        for (int o = 0; o < 16; ++o) accE[bl][o] = 0.f;

    // stage chunk 0: wave wv stages rows {k*16+wv}; lane l writes slot rl*64+l,
    // so the global source is pre-swizzled: float4 (l ^ rl) of the row.
    #pragma unroll
    for (int k = 0; k < 4; ++k) {
        int rl = k * 16 + wv;
        gload_lds16(W4c + (size_t)(r0 + rl) * 1024 + (lane ^ rl), &Wl[0][rl * 64]);
    }
    __syncthreads();                               // drains vmcnt(0)

    #pragma unroll
    for (int ch = 0; ch < 4; ++ch) {
        if (ch < 3) {                              // issue next chunk's loads first
            #pragma unroll
            for (int k = 0; k < 4; ++k) {
                int rl = k * 16 + wv;
                gload_lds16(W4c + (size_t)(r0 + (ch + 1) * 64 + rl) * 1024 + (lane ^ rl),
                            &Wl[(ch + 1) & 1][rl * 64]);
            }
        }
        const float4* Wb = Wl[ch & 1];

        float u[2][16];
        #pragma unroll
        for (int o = 0; o < 16; ++o) {
            float4 w0 = Wb[lane * 64 + ((o * 4 + 0) ^ lane)];
            float4 w1 = Wb[lane * 64 + ((o * 4 + 1) ^ lane)];
            float4 w2 = Wb[lane * 64 + ((o * 4 + 2) ^ lane)];
            float4 w3 = Wb[lane * 64 + ((o * 4 + 3) ^ lane)];
            #pragma unroll
            for (int bl = 0; bl < 2; ++bl)
                u[bl][o] = DOT16S(w0, w1, w2, w3, xs[bl]);
        }

        #pragma unroll
        for (int bl = 0; bl < 2; ++bl) {
            float Lv = 0.f;
            #pragma unroll
            for (int o = 0; o < 16; ++o) Lv += u[bl][o] * vs[bl][o];
            float e = __expf(Lv);
            accZ[bl] += e;
            #pragma unroll
            for (int o = 0; o < 16; ++o) accE[bl][o] += e * u[bl][o];
        }
        __syncthreads();   // barrier + vmcnt(0) drain of loads issued pre-compute
    }

    // Butterfly-reduce the 32 accE values + 2 accZ over the 64 lanes.
    float va = 0.f;
    #pragma unroll
    for (int bl = 0; bl < 2; ++bl) {
        #pragma unroll
        for (int o = 0; o < 16; ++o) {
            float t = accE[bl][o];
            #pragma unroll
            for (int d = 1; d < 64; d <<= 1) t += __shfl_xor(t, d);
            if (lane == bl * 16 + o) va = t;
        }
    }
    float vz = 0.f;
    #pragma unroll
    for (int bl = 0; bl < 2; ++bl) {
        float t = accZ[bl];
        #pragma unroll
        for (int d = 1; d < 64; d <<= 1) t += __shfl_xor(t, d);
        if (lane == bl) vz = t;
    }
    if (lane < 32) {
        int b = wv * 2 + (lane >> 4);
        atomicAdd(&E[b * 256 + c * 16 + (lane & 15)], va);
    }
    if (lane < 2) atomicAdd(&Z[(wv * 2 + lane) * 16 + c], vz);
}

// ---------------------------------------------------------------------------
// launch
// ---------------------------------------------------------------------------
extern "C" void kernel_launch(void* const* d_in, const int* in_sizes, int n_in,
                              void* d_out, int out_size, void* d_ws, size_t ws_size,
                              hipStream_t stream) {
    const float* x = (const float*)d_in[0];        // 8192 floats
    const float* W = (const float*)d_in[1];        // 67108864 floats (256 MB)
    float* out = (float*)d_out;                    // 8192 floats
    float* ws = (float*)d_ws;

    float* E2   = ws + 4096;       // 8192
    float* Z2   = ws + 12288;      // 512
    float* E3   = ws + 12800;      // 8192
    float* Z3   = ws + 20992;      // 512   (zeroed region ends at 21504)
    float* v1   = ws + 21504;      // 8192
    float* vsum = ws + 29696;      // 8192
    float* part = ws + 37888;      // 1048576 (4 MB): 256 x 1024 float4 partials

    hipMemsetAsync(ws, 0, 21504 * sizeof(float), stream);

    // iter 1: uniform softmax -> v1 from Wsum (W pass 1), atomic-free
    k_wsum<<<1024, 256, 0, stream>>>((const float4*)W, (float4*)part);
    k_wred_v1<<<16, 256, 0, stream>>>(part, x, v1);

    // iter 2: logits = <u, v1>  (W pass 2, reverse r for L3 reuse)
    k_route<1><<<dim3(64, 16), 1024, 0, stream>>>(W, x, v1, E2, Z2);
    k_vsum<<<32, 256, 0, stream>>>(E2, Z2, v1, vsum);  // vsum = v1 + squash(E2/Z2)

    // iter 3: logits = <u, v1+v2>  (W pass 3, forward r)
    k_route<0><<<dim3(64, 16), 1024, 0, stream>>>(W, x, vsum, E3, Z3);
    k_vout<<<32, 256, 0, stream>>>(E3, Z3, out);
}